// Round 4
// baseline (220.404 us; speedup 1.0000x reference)
//
#include <hip/hip_runtime.h>

// ---- problem constants ----
#define C_SZ   3
#define IMG_SZ 512
#define G_SZ   32
// per (c,g) GEMM: M = 64*32 = 2048, K = 256, N = 256

typedef short  short8 __attribute__((ext_vector_type(8)));   // 8 bf16 (4 VGPR)
typedef float  f32x4  __attribute__((ext_vector_type(4)));
typedef unsigned short u16;
typedef u16    u16x8  __attribute__((ext_vector_type(8)));

__device__ __forceinline__ u16 f2bf(float f) {
    unsigned u = __float_as_uint(f);
    u += 0x7FFFu + ((u >> 16) & 1u);          // round-to-nearest-even
    return (u16)(u >> 16);
}

__device__ __forceinline__ float tanh_fast(float v) {
    float e = __expf(2.f * v);
    return 1.f - 2.f * __builtin_amdgcn_rcpf(e + 1.f);
}

// ---------- prep: wt3[cg][kb][kg][n][e] = bf16(w[cg][kb*32+kg*8+e][n]) ----------
// Fragment-ordered: lane (kg = lane>>4, r = lane&15) reads its 16B MFMA B-operand
// for (ks=kb, n) at a single contiguous address.
__global__ __launch_bounds__(256)
void prep_wt(const float* __restrict__ w, u16* __restrict__ wt) {
    const int cg = blockIdx.x;        // 0..95
    const int kb = blockIdx.y;        // 0..7
    __shared__ float T[32][260];      // +4 pad: conflict-free column gather
    const int tid = threadIdx.x;
    const float* wb = w + (size_t)cg * 65536 + (size_t)kb * 32 * 256;
    #pragma unroll
    for (int pass = 0; pass < 8; ++pass) {
        int q = pass * 256 + tid;     // 2048 float4 chunks
        int pl = q >> 6, o4 = (q & 63) * 4;
        float4 v = *reinterpret_cast<const float4*>(wb + (size_t)pl * 256 + o4);
        T[pl][o4 + 0] = v.x; T[pl][o4 + 1] = v.y;
        T[pl][o4 + 2] = v.z; T[pl][o4 + 3] = v.w;
    }
    __syncthreads();
    u16* dst = wt + ((size_t)cg * 8 + kb) * 8192;
    #pragma unroll
    for (int h0 = 0; h0 < 4; ++h0) {
        int h = h0 * 256 + tid;       // kg x n chunks, stores fully coalesced
        int kg = h >> 8, n = h & 255;
        u16x8 v;
        #pragma unroll
        for (int e = 0; e < 8; ++e) v[e] = f2bf(T[kg * 8 + e][n]);
        *reinterpret_cast<u16x8*>(dst + (size_t)kg * 2048 + n * 8) = v;
    }
}

// ---------- main GEMM: BM=64 x BN=256, 4 waves (each 64x64) ----------
// NO LDS, NO barriers: every lane loads its A fragment (8 contiguous floats of x)
// and B fragment (16B of fragment-ordered wt) directly from global. Fully
// unrolled K-loop with no stores -> compiler pipelines loads deeply (counted
// vmcnt), waves run completely independently.
__global__ __launch_bounds__(256, 3)
void obf_mfma(const float* __restrict__ x,
              const u16*  __restrict__ wt,
              const float* __restrict__ bias,
              const int*  __restrict__ perm,
              float* __restrict__ out)
{
    // bijective XCD swizzle: 3072 blocks = 8 XCDs x 384; same-cg blocks (and
    // the cg/cg+1 x-line sharers) land on one XCD -> L2 absorbs re-reads.
    const int bid  = blockIdx.x;
    const int sbid = (bid & 7) * 384 + (bid >> 3);
    const int mtile = sbid & 31;      // 0..31
    const int cg    = sbid >> 5;      // 0..95
    const int c = cg >> 5, g = cg & 31;
    const int tid  = threadIdx.x;
    const int lane = tid & 63, wv = tid >> 6;
    const int r = lane & 15, kg = lane >> 4;

    int cp = 0;
    #pragma unroll
    for (int i = 0; i < C_SZ; ++i) if (perm[i] == c) cp = i;

    // A fragment source per mi: row m = mi*16 + r, k-quarter kg.
    // k = ks*32 + kg*8 + e  ->  image row nh*16 + 2*ks + (kg>>1),
    //                           col nw*16 + (kg&1)*8 + e   (8 contiguous floats)
    const float* asrc[4];
    #pragma unroll
    for (int mi = 0; mi < 4; ++mi) {
        int mg = mtile * 64 + mi * 16 + r;
        int b  = mg >> 5, nh = mg & 31, nw = (g - nh) & 31;
        asrc[mi] = x + (((size_t)(b * C_SZ + c) * IMG_SZ + nh * 16 + (kg >> 1)) * IMG_SZ
                        + nw * 16 + (kg & 1) * 8);
    }
    // B fragment source: n = wv*64 + ni*16 + r, 8 contiguous bf16 per (ks,ni)
    const u16* bsrc = wt + (size_t)cg * 65536 + kg * 2048 + (size_t)(wv * 64 + r) * 8;

    f32x4 acc[4][4] = {};

    #pragma unroll
    for (int ks = 0; ks < 8; ++ks) {
        f32x4 alo[4], ahi[4];
        #pragma unroll
        for (int mi = 0; mi < 4; ++mi) {
            alo[mi] = *reinterpret_cast<const f32x4*>(asrc[mi] + ks * 1024);
            ahi[mi] = *reinterpret_cast<const f32x4*>(asrc[mi] + ks * 1024 + 4);
        }
        short8 bf[4];
        #pragma unroll
        for (int ni = 0; ni < 4; ++ni)
            bf[ni] = *reinterpret_cast<const short8*>(bsrc + ks * 8192 + ni * 128);
        short8 af[4];
        #pragma unroll
        for (int mi = 0; mi < 4; ++mi) {
            #pragma unroll
            for (int e = 0; e < 4; ++e) {
                af[mi][e]     = (short)f2bf(alo[mi][e]);
                af[mi][4 + e] = (short)f2bf(ahi[mi][e]);
            }
        }
        #pragma unroll
        for (int mi = 0; mi < 4; ++mi)
            #pragma unroll
            for (int ni = 0; ni < 4; ++ni)
                acc[mi][ni] = __builtin_amdgcn_mfma_f32_16x16x32_bf16(
                    af[mi], bf[ni], acc[mi][ni], 0, 0, 0);
    }

    // ---- epilogue: bias + tanh + un-patch + channel permute ----
    const int cc = lane & 15;
    float bs[4];
    #pragma unroll
    for (int ni = 0; ni < 4; ++ni)
        bs[ni] = bias[(size_t)cg * 256 + wv * 64 + ni * 16 + cc];

    #pragma unroll
    for (int mi = 0; mi < 4; ++mi) {
        #pragma unroll
        for (int reg = 0; reg < 4; ++reg) {
            const int ml = mi * 16 + kg * 4 + reg;
            const int mg = mtile * 64 + ml;
            const int b  = mg >> 5, nh = mg & 31, nw = (g - nh) & 31;
            float* orow = out + ((size_t)(b * C_SZ + cp) * IMG_SZ + nh * 16) * IMG_SZ
                              + nw * 16 + cc;
            #pragma unroll
            for (int ni = 0; ni < 4; ++ni) {
                const int rp = wv * 4 + ni;          // patch-local row
                orow[(size_t)rp * IMG_SZ] = tanh_fast(acc[mi][ni][reg] + bs[ni]);
            }
        }
    }
}

extern "C" void kernel_launch(void* const* d_in, const int* in_sizes, int n_in,
                              void* d_out, int out_size, void* d_ws, size_t ws_size,
                              hipStream_t stream) {
    const float* x    = (const float*)d_in[0];
    const float* w    = (const float*)d_in[1];
    const float* bias = (const float*)d_in[2];
    const int*   perm = (const int*)d_in[3];
    float* out = (float*)d_out;
    u16*   wt  = (u16*)d_ws;          // 96*65536*2 = 12.6 MB scratch

    dim3 pgrid(C_SZ * G_SZ, 8, 1);    // (96,8)
    prep_wt<<<pgrid, 256, 0, stream>>>(w, wt);

    obf_mfma<<<3072, 256, 0, stream>>>(x, wt, bias, perm, out);
}

// Round 6
// 145.682 us; speedup vs baseline: 1.5129x; 1.5129x over previous
//
#include <hip/hip_runtime.h>

// ---- problem constants ----
#define C_SZ   3
#define IMG_SZ 512
// per (c,g) GEMM: M = 64*32 = 2048, K = 256, N = 256

typedef short  short8 __attribute__((ext_vector_type(8)));   // 8 bf16 (4 VGPR)
typedef float  f32x4  __attribute__((ext_vector_type(4)));
typedef unsigned short u16;
typedef u16    u16x8  __attribute__((ext_vector_type(8)));

__device__ __forceinline__ u16 f2bf(float f) {
    unsigned u = __float_as_uint(f);
    u += 0x7FFFu + ((u >> 16) & 1u);          // round-to-nearest-even
    return (u16)(u >> 16);
}

__device__ __forceinline__ float tanh_fast(float v) {
    float e = __expf(2.f * v);
    return 1.f - 2.f * __builtin_amdgcn_rcpf(e + 1.f);
}

// async 16B global->LDS DMA (lane i of the wave lands at ldsbase + i*16)
__device__ __forceinline__ void gload_lds16(const float* g, float* l) {
    __builtin_amdgcn_global_load_lds(
        (const __attribute__((address_space(1))) void*)g,
        (__attribute__((address_space(3))) void*)l, 16, 0, 0);
}

// order-pinned 16B global->VGPR load (counts in vmcnt exactly where issued)
__device__ __forceinline__ short8 gload_b128(const u16* p) {
    short8 d;
    asm volatile("global_load_dwordx4 %0, %1, off"
                 : "=v"(d) : "v"(p) : "memory");
    return d;
}

// ---------- prep: wt3[cg][kb][kg][n][e] = bf16(w[cg][kb*32+kg*8+e][n]) ----------
__global__ __launch_bounds__(256)
void prep_wt(const float* __restrict__ w, u16* __restrict__ wt) {
    const int cg = blockIdx.x;        // 0..95
    const int kb = blockIdx.y;        // 0..7
    __shared__ float T[32][260];      // +4 pad: conflict-free column gather
    const int tid = threadIdx.x;
    const float* wb = w + (size_t)cg * 65536 + (size_t)kb * 32 * 256;
    #pragma unroll
    for (int pass = 0; pass < 8; ++pass) {
        int q = pass * 256 + tid;
        int pl = q >> 6, o4 = (q & 63) * 4;
        float4 v = *reinterpret_cast<const float4*>(wb + (size_t)pl * 256 + o4);
        T[pl][o4 + 0] = v.x; T[pl][o4 + 1] = v.y;
        T[pl][o4 + 2] = v.z; T[pl][o4 + 3] = v.w;
    }
    __syncthreads();
    u16* dst = wt + ((size_t)cg * 8 + kb) * 8192;
    #pragma unroll
    for (int h0 = 0; h0 < 4; ++h0) {
        int h = h0 * 256 + tid;
        int kg = h >> 8, n = h & 255;
        u16x8 v;
        #pragma unroll
        for (int e = 0; e < 8; ++e) v[e] = f2bf(T[kg * 8 + e][n]);
        *reinterpret_cast<u16x8*>(dst + (size_t)kg * 2048 + n * 8) = v;
    }
}

// ---------- main GEMM: BM=64 x BN=256, 4 waves (each 64x64) ----------
// A: fp32 via global_load_lds, 3-buffer ring, 1 stage ahead (R=3 >= d+2, race-free),
//    XOR-swizzled source + XOR-swizzled ds_read (involution, rule #21).
// B: fragment-ordered wt, inline-asm global_load_dwordx4 (vmem order pinned).
// Sync: exactly 6 vmem ops/iter -> s_waitcnt vmcnt(6) + sched_barrier + s_barrier.
__global__ __launch_bounds__(256)
void obf_mfma(const float* __restrict__ x,
              const u16*  __restrict__ wt,
              const float* __restrict__ bias,
              const int*  __restrict__ perm,
              float* __restrict__ out)
{
    // bijective XCD swizzle: 3072 = 8 XCDs x 384
    const int bid  = blockIdx.x;
    const int sbid = (bid & 7) * 384 + (bid >> 3);
    const int mtile = sbid & 31;      // 0..31
    const int cg    = sbid >> 5;      // 0..95
    const int c = cg >> 5, g = cg & 31;
    const int tid  = threadIdx.x;
    const int lane = tid & 63, wv = tid >> 6;
    const int r = lane & 15, kg = lane >> 4;

    __shared__ float As[3][2048];     // 3 x 8KB ring; rows = 32 floats (128B)

    int cp = 0;
    #pragma unroll
    for (int i = 0; i < C_SZ; ++i) if (perm[i] == c) cp = i;

    // staging: thread owns physical chunks q0 = wv*128+lane, q1 = q0+64.
    // chunk q -> row = q>>3, pos = q&7, logical k-chunk lpos = pos ^ (row&7).
    const float* g_src[2];
    #pragma unroll
    for (int j = 0; j < 2; ++j) {
        int q    = wv * 128 + j * 64 + lane;
        int row  = q >> 3;
        int lpos = (q & 7) ^ (row & 7);
        int mg   = mtile * 64 + row;
        int b    = mg >> 5, nh = mg & 31, nw = (g - nh) & 31;
        g_src[j] = x + (((size_t)(b * C_SZ + c) * IMG_SZ + nh * 16 + (lpos >> 2)) * IMG_SZ
                        + nw * 16 + (lpos & 3) * 4);
    }
    // B fragment source (lane-contiguous 16B per (ks,ni))
    const u16* bsrc = wt + (size_t)cg * 65536 + kg * 2048 + (size_t)(wv * 64 + r) * 8;

    // swizzled ds_read float offsets (involution of the source swizzle)
    const int p0 = (((2 * kg)     ^ (r & 7)) * 4);
    const int p1 = (((2 * kg + 1) ^ (r & 7)) * 4);
    const int rbase = r * 32;

    f32x4 acc[4][4] = {};
    short8 bv[2][4];                  // ping-pong, all indices literal after unroll

#define STAGE_A(t) do {                                                \
        float* d_ = &As[(t) % 3][0] + wv * 512;                        \
        gload_lds16(g_src[0] + (size_t)(t) * 1024, d_);                \
        gload_lds16(g_src[1] + (size_t)(t) * 1024, d_ + 256);          \
    } while (0)

    // ---- prologue: stage 0 in flight ----
    STAGE_A(0);
    #pragma unroll
    for (int ni = 0; ni < 4; ++ni)
        bv[0][ni] = gload_b128(bsrc + ni * 128);

    #pragma unroll
    for (int t = 0; t < 8; ++t) {
        if (t < 7) {
            STAGE_A(t + 1);                           // 2 DMA
            #pragma unroll
            for (int ni = 0; ni < 4; ++ni)            // 4 pinned loads
                bv[(t + 1) & 1][ni] = gload_b128(bsrc + (t + 1) * 8192 + ni * 128);
            asm volatile("s_waitcnt vmcnt(6)" ::: "memory");  // drain stage t only
        } else {
            asm volatile("s_waitcnt vmcnt(0)" ::: "memory");
        }
        __builtin_amdgcn_sched_barrier(0);
        __builtin_amdgcn_s_barrier();

        const float* lb = &As[t % 3][0];
        #pragma unroll
        for (int mi = 0; mi < 4; ++mi) {
            f32x4 v0 = *reinterpret_cast<const f32x4*>(lb + mi * 512 + rbase + p0);
            f32x4 v1 = *reinterpret_cast<const f32x4*>(lb + mi * 512 + rbase + p1);
            short8 af;
            af[0] = (short)f2bf(v0[0]); af[1] = (short)f2bf(v0[1]);
            af[2] = (short)f2bf(v0[2]); af[3] = (short)f2bf(v0[3]);
            af[4] = (short)f2bf(v1[0]); af[5] = (short)f2bf(v1[1]);
            af[6] = (short)f2bf(v1[2]); af[7] = (short)f2bf(v1[3]);
            #pragma unroll
            for (int ni = 0; ni < 4; ++ni)
                acc[mi][ni] = __builtin_amdgcn_mfma_f32_16x16x32_bf16(
                    af, bv[t & 1][ni], acc[mi][ni], 0, 0, 0);
        }
    }
#undef STAGE_A

    // ---- epilogue: bias + tanh + un-patch + channel permute ----
    const int cc = lane & 15;
    float bs[4];
    #pragma unroll
    for (int ni = 0; ni < 4; ++ni)
        bs[ni] = bias[(size_t)cg * 256 + wv * 64 + ni * 16 + cc];

    #pragma unroll
    for (int mi = 0; mi < 4; ++mi) {
        #pragma unroll
        for (int reg = 0; reg < 4; ++reg) {
            const int ml = mi * 16 + kg * 4 + reg;
            const int mg = mtile * 64 + ml;
            const int b  = mg >> 5, nh = mg & 31, nw = (g - nh) & 31;
            float* orow = out + ((size_t)(b * C_SZ + cp) * IMG_SZ + nh * 16) * IMG_SZ
                              + nw * 16 + cc;
            #pragma unroll
            for (int ni = 0; ni < 4; ++ni) {
                const int rp = wv * 4 + ni;          // patch-local row
                orow[(size_t)rp * IMG_SZ] = tanh_fast(acc[mi][ni][reg] + bs[ni]);
            }
        }
    }
}

extern "C" void kernel_launch(void* const* d_in, const int* in_sizes, int n_in,
                              void* d_out, int out_size, void* d_ws, size_t ws_size,
                              hipStream_t stream) {
    const float* x    = (const float*)d_in[0];
    const float* w    = (const float*)d_in[1];
    const float* bias = (const float*)d_in[2];
    const int*   perm = (const int*)d_in[3];
    float* out = (float*)d_out;
    u16*   wt  = (u16*)d_ws;          // 96*65536*2 = 12.6 MB scratch

    dim3 pgrid(C_SZ * 32, 8, 1);      // (96,8)
    prep_wt<<<pgrid, 256, 0, stream>>>(w, wt);

    obf_mfma<<<3072, 256, 0, stream>>>(x, wt, bias, perm, out);
}